// Round 8
// baseline (584.682 us; speedup 1.0000x reference)
//
#include <hip/hip_runtime.h>
#include <hip/hip_cooperative_groups.h>

namespace cg = cooperative_groups;

// CapsNet dynamic routing, MI355X. Never materialize u_hat.
// R8: single cooperative kernel for all 3 routing iterations (softmax/s-pass/redsq/agree phases
//     separated by grid.sync) — 13 launches -> 3. Phase math identical to R7.

typedef __attribute__((ext_vector_type(8))) __bf16 bf16x8;
typedef __attribute__((ext_vector_type(4))) float  f32x4;
typedef __attribute__((ext_vector_type(8))) unsigned short u16x8;
typedef __attribute__((ext_vector_type(4))) unsigned int  u32x4;

#define DI __device__ __forceinline__

DI float bf2f(unsigned short u){ unsigned int x = ((unsigned int)u) << 16; return __builtin_bit_cast(float, x); }
DI unsigned int cvtpk(float lo, float hi){            // packed RNE f32->bf16 pair
  unsigned int r;
  asm("v_cvt_pk_bf16_f32 %0, %1, %2" : "=v"(r) : "v"(lo), "v"(hi));
  return r;
}
DI unsigned short f2bf(float f){
  unsigned int u = __builtin_bit_cast(unsigned int, f);
  u += 0x7fffu + ((u >> 16) & 1u);
  return (unsigned short)(u >> 16);
}

constexpr int Ci = 4096, Kk = 32, Jj = 10, Dd = 16, Bb = 128;
constexpr int KI = Ci * Kk;    // 131072, ki = k*4096 + i
constexpr int JDt = Jj * Dd;   // 160
constexpr int NCH = 256, CK = 512;   // s-phase split-K chunks

// workspace layout (bytes)
constexpr size_t OFF_W2 = 0;
constexpr size_t SZ_W2  = (size_t)JDt * KI * 2;       // 41,943,040  w2[m][i], m=jd*32+k
constexpr size_t OFF_XT = OFF_W2 + SZ_W2;
constexpr size_t SZ_XT  = (size_t)KI * Bb * 2;        // 33,554,432  xT[ki][b]
constexpr size_t OFF_XB = OFF_XT + SZ_XT;
constexpr size_t SZ_XB  = (size_t)Bb * KI * 2;        // 33,554,432  xbf[b][ki]
constexpr size_t OFF_BT = OFF_XB + SZ_XB;
constexpr size_t SZ_BT  = (size_t)Jj * Ci * 4;        // 163,840
constexpr size_t OFF_CT = OFF_BT + SZ_BT;
constexpr size_t OFF_VBT = OFF_CT + SZ_BT;
constexpr size_t SZ_VBT = (size_t)JDt * Bb * 2;
constexpr size_t OFF_SP = OFF_VBT + SZ_VBT;
constexpr size_t SZ_SP  = (size_t)NCH * Bb * JDt * 4; // 20,971,520  spart[ch][b][jd]

// ---- pack W: f32 W[i][m] (row 5120) -> bf16 w2[m][i]; [64 i x 512 m] tiles ----
constexpr int WPAD = 522;
__global__ __launch_bounds__(512) void pack_w(const float* __restrict__ W, unsigned short* __restrict__ w2){
  __shared__ unsigned short t16[64 * WPAD];
  const int mt = blockIdx.x % 10, it = blockIdx.x / 10;
  const int m0 = mt * 512, i0 = it * 64;
  #pragma unroll
  for(int u=0; u<16; u++){
    int e = threadIdx.x + 512*u;
    int row = e >> 7, c4 = e & 127;
    float4 v = *(const float4*)(W + (size_t)(i0+row)*5120 + m0 + c4*4);
    unsigned int* p = (unsigned int*)(t16 + row*WPAD + c4*4);
    p[0] = cvtpk(v.x, v.y);
    p[1] = cvtpk(v.z, v.w);
  }
  __syncthreads();
  #pragma unroll
  for(int u=0; u<8; u++){
    int e = threadIdx.x + 512*u;
    int mr = e >> 3, g = e & 7;
    u32x4 o;
    #pragma unroll
    for(int j=0; j<4; j++){
      unsigned int lo = t16[(g*8 + 2*j    )*WPAD + mr];
      unsigned int hi = t16[(g*8 + 2*j + 1)*WPAD + mr];
      o[j] = lo | (hi << 16);
    }
    *(u32x4*)(w2 + (size_t)(m0+mr)*Ci + i0 + g*8) = o;
  }
}

// ---- pack xT + xbf: f32 x[b][ki] -> bf16 xT[ki][b] AND xbf[b][ki]; [64 b x 128 ki] tiles ----
constexpr int XPAD = 134;
__global__ __launch_bounds__(256) void pack_xt(const float* __restrict__ x, unsigned short* __restrict__ xT,
                                               unsigned short* __restrict__ xbf, float* __restrict__ bT){
  __shared__ float tile[64 * XPAD];
  const int bid = blockIdx.x;
  if(bid >= 2048){                                    // zero bT
    ((f32x4*)bT)[(bid-2048)*256 + threadIdx.x] = f32x4{0.f,0.f,0.f,0.f};
    return;
  }
  const int ki0 = (bid >> 1) * 128, b0 = (bid & 1) * 64;
  #pragma unroll
  for(int u=0; u<8; u++){
    int e = threadIdx.x + 256*u;
    int row = e >> 5, q = e & 31;
    float4 v = *(const float4*)(x + (size_t)(b0+row)*KI + ki0 + q*4);
    float2* p = (float2*)(tile + row*XPAD + q*4);
    p[0] = float2{v.x, v.y};
    p[1] = float2{v.z, v.w};
  }
  __syncthreads();
  #pragma unroll
  for(int u=0; u<4; u++){                             // xT
    int e = threadIdx.x + 256*u;
    int kir = e >> 3, g = e & 7;
    u32x4 o;
    #pragma unroll
    for(int j=0; j<4; j++)
      o[j] = cvtpk(tile[(g*8 + 2*j)*XPAD + kir], tile[(g*8 + 2*j + 1)*XPAD + kir]);
    *(u32x4*)(xT + (size_t)(ki0+kir)*Bb + b0 + g*8) = o;
  }
  #pragma unroll
  for(int u=0; u<4; u++){                             // xbf
    int e = threadIdx.x + 256*u;
    int row = e >> 4, sg = e & 15;
    u32x4 o;
    #pragma unroll
    for(int j=0; j<4; j++)
      o[j] = cvtpk(tile[row*XPAD + sg*8 + 2*j], tile[row*XPAD + sg*8 + 2*j + 1]);
    *(u32x4*)(xbf + (size_t)(b0+row)*KI + ki0 + sg*8) = o;
  }
}

// ================= fused cooperative routing kernel =================
__global__ __launch_bounds__(512) void routing(const unsigned short* __restrict__ xbf,
                                               const unsigned short* __restrict__ xT,
                                               const unsigned short* __restrict__ w2,
                                               float* __restrict__ bT,
                                               float* __restrict__ cT,
                                               unsigned short* __restrict__ vbT,
                                               float* __restrict__ spart,
                                               float* __restrict__ vout){
  cg::grid_group grid = cg::this_grid();
  __shared__ __align__(16) char smem[73728];          // aliased per phase
  const int tid = threadIdx.x, lane = tid & 63, wid = tid >> 6;
  const float cu = 1.0f/4096.0f;

  #define XSP(BUF) ((char*)smem + (BUF)*16384)
  #define WSP(BUF) ((char*)smem + 32768 + (BUF)*20480)

  for(int t=0; t<3; ++t){
    // ---- softmax phase (t>0): cT[j][i] = softmax_i(bT[j]) ----
    if(t > 0){
      if(blockIdx.x < Jj){
        const int j = blockIdx.x;
        float* redm = (float*)smem;       // 8
        float* reds = (float*)smem + 8;   // 8
        float vals[8]; float mx = -3.4e38f;
        #pragma unroll
        for(int u=0; u<8; u++){ vals[u] = bT[j*Ci + tid + 512*u]; mx = fmaxf(mx, vals[u]); }
        #pragma unroll
        for(int o=32; o>0; o>>=1) mx = fmaxf(mx, __shfl_xor(mx, o));
        if(lane == 0) redm[wid] = mx;
        __syncthreads();
        mx = fmaxf(fmaxf(fmaxf(redm[0],redm[1]),fmaxf(redm[2],redm[3])),
                   fmaxf(fmaxf(redm[4],redm[5]),fmaxf(redm[6],redm[7])));
        float sm = 0.f;
        #pragma unroll
        for(int u=0; u<8; u++){ vals[u] = expf(vals[u]-mx); sm += vals[u]; }
        #pragma unroll
        for(int o=32; o>0; o>>=1) sm += __shfl_xor(sm, o);
        if(lane == 0) reds[wid] = sm;
        __syncthreads();
        sm = reds[0]+reds[1]+reds[2]+reds[3]+reds[4]+reds[5]+reds[6]+reds[7];
        float inv = 1.0f / sm;
        #pragma unroll
        for(int u=0; u<8; u++) cT[j*Ci + tid + 512*u] = vals[u]*inv;
      }
      grid.sync();
    }

    // ---- s phase: spart[ch][b][jd] partials over this block's 512-ki chunk ----
    {
      const bool useC = (t > 0);
      const int wb = wid & 3, wj = wid >> 2;
      const int ki0 = blockIdx.x * CK;
      const int xb_ = tid >> 3, xsg = tid & 7;
      f32x4 acc[2][5];
      #pragma unroll
      for(int m=0;m<2;m++)
        #pragma unroll
        for(int n=0;n<5;n++) acc[m][n] = f32x4{0.f,0.f,0.f,0.f};

      u16x8 xv0, xv1; u16x8 wv[3]; int ibn;

      #define S_LOAD(STEP) { \
        const int kb = ki0 + (STEP)*64; \
        xv0 = *(const u16x8*)(xbf + (size_t)xb_*KI + kb + xsg*8); \
        xv1 = *(const u16x8*)(xbf + (size_t)(xb_+64)*KI + kb + xsg*8); \
        ibn = kb & (Ci-1); \
        _Pragma("unroll") \
        for(int u=0; u<3; u++){ int e = tid + 512*u; if(e < 1280){ \
          int jd = e>>3, sg = e&7; \
          wv[u] = *(const u16x8*)(w2 + (size_t)jd*KI + kb + sg*8); \
        }} }

      #define S_WRITE(BUF) { \
        *(u16x8*)(XSP(BUF) + xb_*128 + ((xsg*16) ^ ((xb_&7)<<4))) = xv0; \
        *(u16x8*)(XSP(BUF) + (xb_+64)*128 + ((xsg*16) ^ ((xb_&7)<<4))) = xv1; \
        _Pragma("unroll") \
        for(int u=0; u<3; u++){ int e = tid + 512*u; if(e < 1280){ \
          int jd = e>>3, sg = e&7; \
          float f[8]; \
          _Pragma("unroll") \
          for(int q=0;q<8;q++) f[q] = bf2f(wv[u][q]); \
          if(useC){ \
            const float* cp = cT + (jd>>4)*Ci + ibn + sg*8; \
            float4 c0 = *(const float4*)cp; float4 c1 = *(const float4*)(cp+4); \
            f[0]*=c0.x; f[1]*=c0.y; f[2]*=c0.z; f[3]*=c0.w; \
            f[4]*=c1.x; f[5]*=c1.y; f[6]*=c1.z; f[7]*=c1.w; \
          } else { \
            _Pragma("unroll") \
            for(int q=0;q<8;q++) f[q] *= cu; \
          } \
          u32x4 wo; \
          wo[0]=cvtpk(f[0],f[1]); wo[1]=cvtpk(f[2],f[3]); \
          wo[2]=cvtpk(f[4],f[5]); wo[3]=cvtpk(f[6],f[7]); \
          *(u32x4*)(WSP(BUF) + jd*128 + ((sg*16) ^ ((jd&7)<<4))) = wo; \
        }} }

      S_LOAD(0); S_WRITE(0);
      __syncthreads();
      int cur = 0;
      for(int step=0; step<8; ++step){
        if(step < 7) S_LOAD(step+1);
        #pragma unroll
        for(int ks=0; ks<2; ks++){
          const int kk2 = (ks*32 + ((lane>>4)<<3)) * 2;
          bf16x8 a[2];
          #pragma unroll
          for(int m=0;m<2;m++){
            int row = wb*32 + m*16 + (lane&15);
            a[m] = *(const bf16x8*)(XSP(cur) + row*128 + (kk2 ^ ((row&7)<<4)));
          }
          #pragma unroll
          for(int n=0;n<5;n++){
            int row = wj*80 + n*16 + (lane&15);
            bf16x8 bb = *(const bf16x8*)(WSP(cur) + row*128 + (kk2 ^ ((row&7)<<4)));
            acc[0][n] = __builtin_amdgcn_mfma_f32_16x16x32_bf16(a[0], bb, acc[0][n], 0,0,0);
            acc[1][n] = __builtin_amdgcn_mfma_f32_16x16x32_bf16(a[1], bb, acc[1][n], 0,0,0);
          }
        }
        if(step < 7) S_WRITE(cur^1);
        __syncthreads();
        cur ^= 1;
      }
      float* sp = spart + (size_t)blockIdx.x * (Bb*JDt);
      #pragma unroll
      for(int m=0;m<2;m++)
        #pragma unroll
        for(int n=0;n<5;n++)
          #pragma unroll
          for(int r=0;r<4;r++){
            int b  = wb*32 + m*16 + ((lane>>4)<<2) + r;
            int jd = wj*80 + n*16 + (lane&15);
            sp[b*JDt + jd] = acc[m][n][r];
          }
    }
    grid.sync();

    // ---- redsq phase: v[b] = squash(sum_ch spart); writes vout + vbT ----
    if(blockIdx.x < Bb){
      const int b = blockIdx.x;
      float* sred = (float*)smem;            // 6*160
      float* sq   = (float*)smem + 6*JDt;    // 160
      float* scal = (float*)smem + 7*JDt;    // 16
      float s = 0.f;
      if(tid < 240){
        const int g = tid % 40, cg2 = tid / 40;
        f32x4 a = {0.f,0.f,0.f,0.f};
        for(int ch=cg2; ch<NCH; ch+=6)
          a += *(const f32x4*)(spart + (size_t)ch*(Bb*JDt) + b*JDt + g*4);
        *(f32x4*)&sred[cg2*JDt + g*4] = a;
      }
      __syncthreads();
      if(tid < JDt){
        #pragma unroll
        for(int c=0;c<6;c++) s += sred[c*JDt + tid];
        sq[tid] = s*s;
      }
      __syncthreads();
      if(tid < Dd){
        float m = 0.f;
        #pragma unroll
        for(int j=0;j<Jj;j++) m += sq[j*Dd + tid];
        scal[tid] = sqrtf(m) / (1.0f + m);
      }
      __syncthreads();
      if(tid < JDt){
        float v = s * scal[tid & (Dd-1)];
        vout[b*JDt + tid] = v;
        vbT[tid*Bb + b] = f2bf(v);
      }
    }
    grid.sync();

    // ---- agree phase (t<2): 8 waves = 2 concurrent 64-ki strips x 4 iterations ----
    if(t < 2){
      const int p = wid >> 2, wq = wid & 3;
      const int wj = wq & 1, wk = wq >> 1;
      const int bsl = (lane>>4)<<3;
      for(int si=0; si<4; ++si){
        const int ki0 = (blockIdx.x*8 + si*2 + p) * 64;
        f32x4 acc[5][2];
        #pragma unroll
        for(int m=0;m<5;m++){ acc[m][0]=f32x4{0,0,0,0}; acc[m][1]=f32x4{0,0,0,0}; }
        #pragma unroll
        for(int ks=0; ks<4; ks++){
          bf16x8 af[5];
          #pragma unroll
          for(int m=0;m<5;m++){
            int jd = wj*80 + m*16 + (lane&15);
            af[m] = *(const bf16x8*)(vbT + jd*Bb + ks*32 + bsl);
          }
          #pragma unroll
          for(int n=0;n<2;n++){
            int kir = ki0 + wk*32 + n*16 + (lane&15);
            bf16x8 bf_ = *(const bf16x8*)(xT + (size_t)kir*Bb + ks*32 + bsl);
            #pragma unroll
            for(int m=0;m<5;m++)
              acc[m][n] = __builtin_amdgcn_mfma_f32_16x16x32_bf16(af[m], bf_, acc[m][n], 0,0,0);
          }
        }
        const int ibase = ki0 & (Ci-1);
        #pragma unroll
        for(int m=0;m<5;m++){
          int j = wj*5 + m;
          #pragma unroll
          for(int n=0;n<2;n++){
            int colg = ki0 + wk*32 + n*16 + (lane&15);
            float s2 = 0.f;
            #pragma unroll
            for(int r=0;r<4;r++){
              int jdrow = wj*80 + m*16 + ((lane>>4)<<2) + r;
              s2 += acc[m][n][r] * bf2f(w2[(size_t)jdrow*KI + colg]);
            }
            s2 += __shfl_xor(s2, 16);
            s2 += __shfl_xor(s2, 32);
            if(lane < 16){
              int ig = ibase + wk*32 + n*16 + lane;
              atomicAdd(bT + j*Ci + ig, s2 * (1.0f/128.0f));
            }
          }
        }
      }
      grid.sync();
    }
  }
  #undef S_LOAD
  #undef S_WRITE
  #undef XSP
  #undef WSP
}

extern "C" void kernel_launch(void* const* d_in, const int* in_sizes, int n_in,
                              void* d_out, int out_size, void* d_ws, size_t ws_size,
                              hipStream_t stream) {
  const float* x = (const float*)d_in[0];
  const float* W = (const float*)d_in[1];
  float* out = (float*)d_out;
  char* ws = (char*)d_ws;
  const unsigned short* w2  = (const unsigned short*)(ws + OFF_W2);
  const unsigned short* xT  = (const unsigned short*)(ws + OFF_XT);
  const unsigned short* xbf = (const unsigned short*)(ws + OFF_XB);
  float* bT           = (float*)(ws + OFF_BT);
  float* cT           = (float*)(ws + OFF_CT);
  unsigned short* vbT = (unsigned short*)(ws + OFF_VBT);
  float* spart        = (float*)(ws + OFF_SP);

  pack_w<<<640, 512, 0, stream>>>(W, (unsigned short*)w2);
  pack_xt<<<2088, 256, 0, stream>>>(x, (unsigned short*)xT, (unsigned short*)xbf, bT);

  void* args[] = { (void*)&xbf, (void*)&xT, (void*)&w2, (void*)&bT,
                   (void*)&cT, (void*)&vbT, (void*)&spart, (void*)&out };
  hipLaunchCooperativeKernel((const void*)routing, dim3(NCH), dim3(512), args, 0, stream);
}

// Round 9
// 229.701 us; speedup vs baseline: 2.5454x; 2.5454x over previous
//
#include <hip/hip_runtime.h>

// CapsNet dynamic routing, MI355X. Never materialize u_hat.
// R9: routing kernels byte-identical to R2 (best measured: 228.4us). Single-variable change:
//     pack side only — R7's clean pack_w + linear pack_x cast (xT dropped; agree stages from xbf).

typedef __attribute__((ext_vector_type(8))) __bf16 bf16x8;
typedef __attribute__((ext_vector_type(4))) float  f32x4;
typedef __attribute__((ext_vector_type(8))) unsigned short u16x8;
typedef __attribute__((ext_vector_type(4))) unsigned int  u32x4;

#define DI __device__ __forceinline__

DI float bf2f(unsigned short u){ unsigned int x = ((unsigned int)u) << 16; return __builtin_bit_cast(float, x); }
DI unsigned short f2bf(float f){
  unsigned int u = __builtin_bit_cast(unsigned int, f);
  u += 0x7fffu + ((u >> 16) & 1u);            // round-to-nearest-even
  return (unsigned short)(u >> 16);
}
DI unsigned int cvtpk(float lo, float hi){    // packed RNE f32->bf16 pair
  unsigned int r;
  asm("v_cvt_pk_bf16_f32 %0, %1, %2" : "=v"(r) : "v"(lo), "v"(hi));
  return r;
}

constexpr int Ci = 4096, Kk = 32, Jj = 10, Dd = 16, Bb = 128;
constexpr int KI = Ci * Kk;    // 131072 flattened (k,i), ki = k*4096 + i
constexpr int JDt = Jj * Dd;   // 160, jd = j*16 + d
constexpr int NCH = 256, CK = 512;  // s-pass split-K chunks

// workspace layout (bytes)
constexpr size_t OFF_XB = 0;
constexpr size_t SZ_XB  = (size_t)Bb * KI * 2;        // 33,554,432  xbf[b][ki]
constexpr size_t OFF_W2 = OFF_XB + SZ_XB;
constexpr size_t SZ_W2  = (size_t)JDt * KI * 2;       // 41,943,040  w2[m][i], m=jd*32+k
constexpr size_t OFF_BT = OFF_W2 + SZ_W2;
constexpr size_t SZ_BT  = (size_t)Jj * Ci * 4;        // 163,840  bT[j][i]
constexpr size_t OFF_CT = OFF_BT + SZ_BT;             // cT[j][i]
constexpr size_t OFF_VBT = OFF_CT + SZ_BT;
constexpr size_t SZ_VBT = (size_t)JDt * Bb * 2;       // vbT[jd][b]
constexpr size_t OFF_SP = OFF_VBT + SZ_VBT;
constexpr size_t SZ_SP  = (size_t)NCH * Bb * JDt * 4; // 20,971,520  spart[ch][b][jd]

// ---- pack W: f32 W[i][m] (row 5120) -> bf16 w2[m][i]; [64 i x 512 m] tiles, contiguous 2KB reads ----
constexpr int WPAD = 522;
__global__ __launch_bounds__(512) void pack_w(const float* __restrict__ W, unsigned short* __restrict__ w2){
  __shared__ unsigned short t16[64 * WPAD];
  const int mt = blockIdx.x % 10, it = blockIdx.x / 10;
  const int m0 = mt * 512, i0 = it * 64;
  #pragma unroll
  for(int u=0; u<16; u++){
    int e = threadIdx.x + 512*u;
    int row = e >> 7, c4 = e & 127;
    float4 v = *(const float4*)(W + (size_t)(i0+row)*5120 + m0 + c4*4);
    unsigned int* p = (unsigned int*)(t16 + row*WPAD + c4*4);
    p[0] = cvtpk(v.x, v.y);
    p[1] = cvtpk(v.z, v.w);
  }
  __syncthreads();
  #pragma unroll
  for(int u=0; u<8; u++){
    int e = threadIdx.x + 512*u;
    int mr = e >> 3, g = e & 7;
    u32x4 o;
    #pragma unroll
    for(int j=0; j<4; j++){
      unsigned int lo = t16[(g*8 + 2*j    )*WPAD + mr];
      unsigned int hi = t16[(g*8 + 2*j + 1)*WPAD + mr];
      o[j] = lo | (hi << 16);
    }
    *(u32x4*)(w2 + (size_t)(m0+mr)*Ci + i0 + g*8) = o;
  }
}

// ---- pack x: linear f32 -> bf16 cast (no transpose); tail blocks zero bT ----
__global__ __launch_bounds__(256) void pack_x(const float* __restrict__ x, unsigned short* __restrict__ xbf,
                                              float* __restrict__ bT){
  const int bid = blockIdx.x;
  if(bid >= 8192){                                    // zero bT: 40 blocks x 256 x 16B
    ((f32x4*)bT)[(bid-8192)*256 + threadIdx.x] = f32x4{0.f,0.f,0.f,0.f};
    return;
  }
  const size_t e = (size_t)bid * 256 + threadIdx.x;   // 8 elems each
  const float4* xv = (const float4*)x;
  float4 a = xv[e*2], b = xv[e*2+1];
  u32x4 o;
  o[0]=cvtpk(a.x,a.y); o[1]=cvtpk(a.z,a.w);
  o[2]=cvtpk(b.x,b.y); o[3]=cvtpk(b.z,b.w);
  *(u32x4*)(xbf + e*8) = o;
}

// ---- softmax over i per class j (R2 verbatim) ----
__global__ __launch_bounds__(256) void softmax_k(const float* __restrict__ bT, float* __restrict__ cT){
  const int j = blockIdx.x, tid = threadIdx.x, lane = tid & 63, wid = tid >> 6;
  __shared__ float red[4];
  float vals[16];
  float mx = -3.4e38f;
  #pragma unroll
  for(int u=0; u<16; u++){ vals[u] = bT[j*Ci + tid + 256*u]; mx = fmaxf(mx, vals[u]); }
  #pragma unroll
  for(int o=32; o>0; o>>=1) mx = fmaxf(mx, __shfl_xor(mx, o));
  if(lane == 0) red[wid] = mx;
  __syncthreads();
  mx = fmaxf(fmaxf(red[0],red[1]), fmaxf(red[2],red[3]));
  float sm = 0.f;
  #pragma unroll
  for(int u=0; u<16; u++){ vals[u] = expf(vals[u]-mx); sm += vals[u]; }
  #pragma unroll
  for(int o=32; o>0; o>>=1) sm += __shfl_xor(sm, o);
  __syncthreads();
  if(lane == 0) red[wid] = sm;
  __syncthreads();
  sm = red[0]+red[1]+red[2]+red[3];
  float inv = 1.0f / sm;
  #pragma unroll
  for(int u=0; u<16; u++) cT[j*Ci + tid + 256*u] = vals[u]*inv;
}

// ---- s-pass (R2 verbatim): 8 waves, wave = [32 b x 80 jd] of MFMA 16x16x32; 2-barrier loop ----
__global__ __launch_bounds__(512) void s_pass(const unsigned short* __restrict__ xb,
                                              const unsigned short* __restrict__ w2,
                                              const float* __restrict__ cT,
                                              float* __restrict__ spart){
  __shared__ unsigned short xs[128*64];    // [b][k] rows 128B, XOR-swizzled
  __shared__ unsigned short wsm[160*64];   // [jd][k] rows 128B, XOR-swizzled, pre-scaled by c
  const int tid = threadIdx.x, lane = tid & 63, wid = tid >> 6;
  const int wb = wid & 3, wj = wid >> 2;
  const int ki0 = blockIdx.x * CK;
  f32x4 acc[2][5];
  const f32x4 z = {0.f,0.f,0.f,0.f};
  #pragma unroll
  for(int m=0;m<2;m++){ acc[m][0]=z; acc[m][1]=z; acc[m][2]=z; acc[m][3]=z; acc[m][4]=z; }

  for(int step=0; step<CK/64; ++step){
    const int kb = ki0 + step*64;
    const int ib = kb & (Ci-1);       // chunk stays inside one k-slab, i base
    #pragma unroll
    for(int u=0; u<2; u++){           // stage x tile [128 b][64 ki]
      int e = tid + 512*u;
      int b = e >> 3, sg = e & 7;
      u16x8 v = *(const u16x8*)(xb + (size_t)b*KI + kb + sg*8);
      *(u16x8*)((char*)xs + b*128 + ((sg*16) ^ ((b&7)<<4))) = v;
    }
    #pragma unroll
    for(int u=0; u<3; u++){           // stage w tile [160 jd][64 ki] * c[i][j]
      int e = tid + 512*u;
      if(e < 1280){
        int jd = e >> 3, sg = e & 7;
        u16x8 v = *(const u16x8*)(w2 + (size_t)jd*KI + kb + sg*8);
        float cc[8];
        if(cT){
          const float* cp = cT + (jd>>4)*Ci + ib + sg*8;
          float4 c0 = *(const float4*)cp;
          float4 c1 = *(const float4*)(cp+4);
          cc[0]=c0.x; cc[1]=c0.y; cc[2]=c0.z; cc[3]=c0.w;
          cc[4]=c1.x; cc[5]=c1.y; cc[6]=c1.z; cc[7]=c1.w;
        } else {
          #pragma unroll
          for(int q=0;q<8;q++) cc[q] = (1.0f/4096.0f);
        }
        u16x8 o;
        #pragma unroll
        for(int q=0;q<8;q++) o[q] = f2bf(bf2f(v[q])*cc[q]);
        *(u16x8*)((char*)wsm + jd*128 + ((sg*16) ^ ((jd&7)<<4))) = o;
      }
    }
    __syncthreads();
    #pragma unroll
    for(int ks=0; ks<2; ks++){
      const int kk2 = (ks*32 + ((lane>>4)<<3)) * 2;   // byte offset of 8-k group
      bf16x8 a[2];
      #pragma unroll
      for(int m=0;m<2;m++){
        int row = wb*32 + m*16 + (lane&15);
        a[m] = *(const bf16x8*)((const char*)xs + row*128 + (kk2 ^ ((row&7)<<4)));
      }
      #pragma unroll
      for(int n=0;n<5;n++){
        int row = wj*80 + n*16 + (lane&15);
        bf16x8 bb = *(const bf16x8*)((const char*)wsm + row*128 + (kk2 ^ ((row&7)<<4)));
        acc[0][n] = __builtin_amdgcn_mfma_f32_16x16x32_bf16(a[0], bb, acc[0][n], 0,0,0);
        acc[1][n] = __builtin_amdgcn_mfma_f32_16x16x32_bf16(a[1], bb, acc[1][n], 0,0,0);
      }
    }
    __syncthreads();
  }
  float* sp = spart + (size_t)blockIdx.x * (Bb*JDt);
  #pragma unroll
  for(int m=0;m<2;m++)
    #pragma unroll
    for(int n=0;n<5;n++)
      #pragma unroll
      for(int r=0;r<4;r++){
        int b  = wb*32 + m*16 + ((lane>>4)<<2) + r;     // D-frag: row=(lane>>4)*4+r
        int jd = wj*80 + n*16 + (lane&15);              //          col=lane&15
        sp[b*JDt + jd] = acc[m][n][r];
      }
}

// ---- reduce split-K partials + squash (R2 verbatim) ----
__global__ __launch_bounds__(256) void redsq(const float* __restrict__ spart,
                                             float* __restrict__ vout,
                                             unsigned short* __restrict__ vbT){
  const int b = blockIdx.x, tid = threadIdx.x;
  __shared__ float sq[JDt];
  __shared__ float scale[Dd];
  float s = 0.f;
  if(tid < JDt){
    const float* p = spart + b*JDt + tid;
    #pragma unroll 8
    for(int ch=0; ch<NCH; ch++) s += p[(size_t)ch*(Bb*JDt)];
    sq[tid] = s*s;
  }
  __syncthreads();
  if(tid < Dd){
    float m = 0.f;
    #pragma unroll
    for(int j=0;j<Jj;j++) m += sq[j*Dd + tid];
    scale[tid] = sqrtf(m) / (1.0f + m);    // v = s * sqrt(m)/(1+m)
  }
  __syncthreads();
  if(tid < JDt){
    float v = s * scale[tid & (Dd-1)];
    vout[b*JDt + tid] = v;
    vbT[tid*Bb + b] = f2bf(v);
  }
}

// ---- agree pass (R2 verbatim): LDS-staged, epilogue dots W2, atomicAdd -> bT ----
__global__ __launch_bounds__(256) void agree_pass(const unsigned short* __restrict__ xb,
                                                  const unsigned short* __restrict__ vbT,
                                                  const unsigned short* __restrict__ w2,
                                                  float* __restrict__ bT){
  __shared__ unsigned short xsT[64*128];   // [ki][b] rows 256B, swizzled (16 KB)
  __shared__ unsigned short vsm[160*128];  // [jd][b] rows 256B, swizzled (40 KB)
  const int tid = threadIdx.x, lane = tid & 63, wid = tid >> 6;
  const int wj = wid & 1, wk = wid >> 1;
  const int ki0 = blockIdx.x * 64;
  #pragma unroll
  for(int u=0; u<4; u++){                  // stage x transposed
    int e = tid + 256*u;
    int b = e >> 3, sg = e & 7;
    u16x8 v = *(const u16x8*)(xb + (size_t)b*KI + ki0 + sg*8);
    #pragma unroll
    for(int q=0; q<8; q++){
      int kil = sg*8 + q;
      *(unsigned short*)((char*)xsT + kil*256 + ((b*2) ^ ((kil&7)<<4))) = v[q];
    }
  }
  #pragma unroll
  for(int u=0; u<10; u++){                 // stage v
    int e = tid + 256*u;
    int jd = e >> 4, sg = e & 15;
    u16x8 v = *(const u16x8*)(vbT + jd*Bb + sg*8);
    *(u16x8*)((char*)vsm + jd*256 + ((sg*16) ^ ((jd&7)<<4))) = v;
  }
  __syncthreads();
  f32x4 acc[5][2];
  const f32x4 z = {0.f,0.f,0.f,0.f};
  #pragma unroll
  for(int m=0;m<5;m++){ acc[m][0]=z; acc[m][1]=z; }
  #pragma unroll
  for(int ks=0; ks<4; ks++){
    const int b2 = (ks*32 + ((lane>>4)<<3)) * 2;
    bf16x8 bfr[2];
    #pragma unroll
    for(int n=0;n<2;n++){
      int row = wk*32 + n*16 + (lane&15);
      bfr[n] = *(const bf16x8*)((const char*)xsT + row*256 + (b2 ^ ((row&7)<<4)));
    }
    #pragma unroll
    for(int m=0;m<5;m++){
      int row = wj*80 + m*16 + (lane&15);
      bf16x8 af = *(const bf16x8*)((const char*)vsm + row*256 + (b2 ^ ((row&7)<<4)));
      acc[m][0] = __builtin_amdgcn_mfma_f32_16x16x32_bf16(af, bfr[0], acc[m][0], 0,0,0);
      acc[m][1] = __builtin_amdgcn_mfma_f32_16x16x32_bf16(af, bfr[1], acc[m][1], 0,0,0);
    }
  }
  const int ibase = ki0 & (Ci-1);
  #pragma unroll
  for(int m=0;m<5;m++){
    int j = wj*5 + m;
    #pragma unroll
    for(int n=0;n<2;n++){
      int colg = ki0 + wk*32 + n*16 + (lane&15);
      float s = 0.f;
      #pragma unroll
      for(int r=0;r<4;r++){
        int jdrow = wj*80 + m*16 + ((lane>>4)<<2) + r;   // = j*16 + d
        s += acc[m][n][r] * bf2f(w2[(size_t)jdrow*KI + colg]);
      }
      s += __shfl_xor(s, 16);      // lanes l and l^16/l^32 share the same column (i)
      s += __shfl_xor(s, 32);
      if(lane < 16){
        int ig = ibase + wk*32 + n*16 + lane;
        atomicAdd(bT + j*Ci + ig, s * (1.0f/128.0f));
      }
    }
  }
}

extern "C" void kernel_launch(void* const* d_in, const int* in_sizes, int n_in,
                              void* d_out, int out_size, void* d_ws, size_t ws_size,
                              hipStream_t stream) {
  const float* x = (const float*)d_in[0];
  const float* W = (const float*)d_in[1];
  float* out = (float*)d_out;
  char* ws = (char*)d_ws;
  unsigned short* xbf = (unsigned short*)(ws + OFF_XB);
  unsigned short* w2  = (unsigned short*)(ws + OFF_W2);
  float* bT           = (float*)(ws + OFF_BT);
  float* cT           = (float*)(ws + OFF_CT);
  unsigned short* vbT = (unsigned short*)(ws + OFF_VBT);
  float* spart        = (float*)(ws + OFF_SP);

  pack_w<<<640, 512, 0, stream>>>(W, w2);
  pack_x<<<8232, 256, 0, stream>>>(x, xbf, bT);       // tail 40 blocks zero bT
  for(int t=0; t<3; t++){
    if(t > 0) softmax_k<<<Jj, 256, 0, stream>>>(bT, cT);
    s_pass<<<NCH, 512, 0, stream>>>(xbf, w2, (t==0)? nullptr : cT, spart);
    redsq<<<Bb, 256, 0, stream>>>(spart, out, vbT);
    if(t < 2) agree_pass<<<KI/64, 256, 0, stream>>>(xbf, vbT, w2, bT);
  }
}